// Round 4
// baseline (57656.525 us; speedup 1.0000x reference)
//
#include <hip/hip_runtime.h>
#include <stdint.h>
#include <stddef.h>

typedef _Float16 h2 __attribute__((ext_vector_type(2)));

#define T_STEPS 32768
#define HDIM    256

__device__ __forceinline__ float sigmoidf_(float x) {
    return 1.0f / (1.0f + __expf(-x));
}
__device__ __forceinline__ float tanhf_(float x) {
    float e2 = __expf(2.0f * x);
    return 1.0f - 2.0f / (e2 + 1.0f);
}
__device__ __forceinline__ h2 bc_(uint32_t u) { return __builtin_bit_cast(h2, u); }

// One block, 1024 threads = 16 waves = 4 waves/SIMD -> hard VGPR budget 128
// (the allocator's preferred target in R2/R3; design fits UNDER it: ~123).
// Thread (wave w, lane l): quarter qq = l>>4, row ri = w*16 + (l&15).
// Owns GRU rows {ri, 256+ri, 512+ri}, cols [qq*64, qq*64+64): 96 f16-pair regs,
// asm-pinned so loads can't be sunk into the loop (R2/R3 failure mode).
// gi/bhh constants folded into 3 regs via lane-group seeding:
//   q0 seeds b_hh, q1 seeds w_x*x, q2 seeds w_dt*dt, q3 seeds b_ih,
// so the quarter reduction yields gi+gh directly (n-gate input side kept in a
// separate accumulator because n = tanh(i_n + r*h_n)).
__global__ __launch_bounds__(1024, 4)
void aether_gru_kernel(const float* __restrict__ xg,
                       const float* __restrict__ wih,
                       const float* __restrict__ whh,
                       const float* __restrict__ bih,
                       const float* __restrict__ bhh,
                       const float* __restrict__ wfc,
                       const float* __restrict__ bfc,
                       float* __restrict__ out) {
    const int tid  = threadIdx.x;
    const int lane = tid & 63;
    const int w    = tid >> 6;              // wave 0..15
    const int qq   = lane >> 4;             // column quarter 0..3
    const int ri   = w * 16 + (lane & 15);  // result row 0..255

    __shared__ float xlds[T_STEPS + 2];
    __shared__ __align__(16) _Float16 hbuf[2][HDIM];
    __shared__ float pp[2][16];

    // ---- stage x into LDS (coalesced float4, 8 per thread) ----
    {
        const float4* xs4 = (const float4*)xg;
        float4* xd4 = (float4*)xlds;
        #pragma unroll
        for (int j = 0; j < T_STEPS / 4 / 1024; ++j)
            xd4[tid + 1024 * j] = xs4[tid + 1024 * j];
        if (tid == 0) { xlds[T_STEPS] = 0.0f; xlds[T_STEPS + 1] = 0.0f; }
    }

    // ---- weights: 3 gates x 32 f16-pairs (64 cols each), bit-packed ----
    uint32_t wr[32], wz[32], wn[32];
    {
        const float2* p = (const float2*)(whh + (size_t)ri * HDIM + qq * 64);
        #pragma unroll
        for (int k = 0; k < 32; ++k) {
            float2 v = p[k]; h2 q; q.x = (_Float16)v.x; q.y = (_Float16)v.y;
            wr[k] = __builtin_bit_cast(uint32_t, q);
        }
    }
    {
        const float2* p = (const float2*)(whh + (size_t)(HDIM + ri) * HDIM + qq * 64);
        #pragma unroll
        for (int k = 0; k < 32; ++k) {
            float2 v = p[k]; h2 q; q.x = (_Float16)v.x; q.y = (_Float16)v.y;
            wz[k] = __builtin_bit_cast(uint32_t, q);
        }
    }
    {
        const float2* p = (const float2*)(whh + (size_t)(2 * HDIM + ri) * HDIM + qq * 64);
        #pragma unroll
        for (int k = 0; k < 32; ++k) {
            float2 v = p[k]; h2 q; q.x = (_Float16)v.x; q.y = (_Float16)v.y;
            wn[k] = __builtin_bit_cast(uint32_t, q);
        }
    }
    // pin: forces residency, blocks sinking/remat of the staging loads
    #pragma unroll
    for (int k = 0; k < 32; ++k) {
        asm volatile("" : "+v"(wr[k]));
        asm volatile("" : "+v"(wz[k]));
        asm volatile("" : "+v"(wn[k]));
    }

    // ---- per-lane-group seed constants (3 regs cover all 12 scalars) ----
    // gate r -> u0, gate z -> u1, gate n -> u2
    float u0, u1, u2;
    {
        const int g0 = ri, g1 = HDIM + ri, g2 = 2 * HDIM + ri;
        if (qq == 0)      { u0 = bhh[g0];         u1 = bhh[g1];         u2 = bhh[g2]; }
        else if (qq == 1) { u0 = wih[2 * g0];     u1 = wih[2 * g1];     u2 = wih[2 * g2]; }
        else if (qq == 2) { u0 = wih[2 * g0 + 1]; u1 = wih[2 * g1 + 1]; u2 = wih[2 * g2 + 1]; }
        else              { u0 = bih[g0];         u1 = bih[g1];         u2 = bih[g2]; }
    }
    const float wf = wfc[ri];
    const float bf = bfc[0];

    if (tid < HDIM) hbuf[0][tid] = (_Float16)0.0f;
    __syncthreads();

    // ---- sequential state (uniform across threads -> uniform branches) ----
    float hprev    = 0.0f;
    float last_val = xlds[0] + 1.24f;       // xs[0] + (2*THRESHOLD + 1.0)
    float last_t   = 0.0f;
    int   cnt      = 0;
    int   cur      = 0;                     // hbuf read index
    int   pe       = 0;                     // pp parity
    float cur_pred = 0.0f;

    float xc = xlds[0];
    float xn = xlds[1];

    float* recon = out;
    float* idxp  = out + T_STEPS + 1;

    for (int t = 0; t < T_STEPS; ++t) {
        float xf = xlds[t + 2];                      // LDS prefetch, 2 ahead
        const float tf = (float)t;
        const bool ev = fabsf(xc - last_val) >= 0.12f;

        if (ev) {
            const float dtv = (tf - last_t) * 0.01f;
            // quarter seeds: q0->b_hh, q1->wx*xc, q2->wdt*dtv, q3->b_ih
            const float sel = (qq == 1) ? xc : ((qq == 2) ? dtv : 1.0f);
            const float s0 = u0 * sel, s1 = u1 * sel, s2 = u2 * sel;
            float ar = s0;
            float az = s1;
            float an = (qq == 0) ? s2 : 0.0f;        // hidden side of n
            float ai = (qq == 0) ? 0.0f : s2;        // input  side of n

            const uint4* hb = (const uint4*)(&hbuf[cur][qq * 64]);
            #pragma unroll
            for (int c = 0; c < 8; ++c) {
                uint4 q = hb[c];                     // 8 f16, broadcast x16 lanes
                h2 p0 = __builtin_bit_cast(h2, q.x);
                h2 p1 = __builtin_bit_cast(h2, q.y);
                h2 p2 = __builtin_bit_cast(h2, q.z);
                h2 p3 = __builtin_bit_cast(h2, q.w);
                const int k = c * 4;
                ar = __builtin_amdgcn_fdot2(bc_(wr[k + 0]), p0, ar, false);
                az = __builtin_amdgcn_fdot2(bc_(wz[k + 0]), p0, az, false);
                an = __builtin_amdgcn_fdot2(bc_(wn[k + 0]), p0, an, false);
                ar = __builtin_amdgcn_fdot2(bc_(wr[k + 1]), p1, ar, false);
                az = __builtin_amdgcn_fdot2(bc_(wz[k + 1]), p1, az, false);
                an = __builtin_amdgcn_fdot2(bc_(wn[k + 1]), p1, an, false);
                ar = __builtin_amdgcn_fdot2(bc_(wr[k + 2]), p2, ar, false);
                az = __builtin_amdgcn_fdot2(bc_(wz[k + 2]), p2, az, false);
                an = __builtin_amdgcn_fdot2(bc_(wn[k + 2]), p2, an, false);
                ar = __builtin_amdgcn_fdot2(bc_(wr[k + 3]), p3, ar, false);
                az = __builtin_amdgcn_fdot2(bc_(wz[k + 3]), p3, az, false);
                an = __builtin_amdgcn_fdot2(bc_(wn[k + 3]), p3, an, false);
            }
            // combine quarters: lanes 0..15 get full sums
            ar += __shfl_down(ar, 32); az += __shfl_down(az, 32);
            an += __shfl_down(an, 32); ai += __shfl_down(ai, 32);
            ar += __shfl_down(ar, 16); az += __shfl_down(az, 16);
            an += __shfl_down(an, 16); ai += __shfl_down(ai, 16);

            const float r = sigmoidf_(ar);
            const float z = sigmoidf_(az);
            const float n = tanhf_(fmaf(r, an, ai));
            const float hnew = fmaf(z, hprev, (1.0f - z) * n);
            hprev = hnew;                            // valid on lanes 0..15

            if ((lane >> 4) == 0) hbuf[cur ^ 1][ri] = (_Float16)hnew;

            // fc partial: zero lanes >=16, reduce 16 -> lane 0
            float pv = (lane < 16) ? hnew * wf : 0.0f;
            pv += __shfl_down(pv, 8);
            pv += __shfl_down(pv, 4);
            pv += __shfl_down(pv, 2);
            pv += __shfl_down(pv, 1);
            if (lane == 0) pp[pe][w] = pv;
            if (tid == 0) idxp[cnt] = tf;            // ascending -> sorted

            last_val = xc;
            last_t   = tf;
            cnt++;

            __syncthreads();                          // publish hbuf + pp
            cur ^= 1;
            if (tid == 0) {
                const float* q = &pp[pe][0];
                float a = 0.0f;
                #pragma unroll
                for (int j = 0; j < 16; ++j) a += q[j];
                cur_pred = a + bf;
            }
            pe ^= 1;
        }

        if (tid == 0) recon[t] = cur_pred;            // piecewise-constant pred
        xc = xn; xn = xf;
    }

    if (tid == 0) out[T_STEPS] = (float)cnt;          // n_events
    for (int j = cnt + tid; j < T_STEPS; j += 1024)
        idxp[j] = 32768.0f;                           // pad with T
}

extern "C" void kernel_launch(void* const* d_in, const int* in_sizes, int n_in,
                              void* d_out, int out_size, void* d_ws, size_t ws_size,
                              hipStream_t stream) {
    const float* x    = (const float*)d_in[0];
    const float* wih  = (const float*)d_in[1];
    const float* whh  = (const float*)d_in[2];
    const float* bih  = (const float*)d_in[3];
    const float* bhh  = (const float*)d_in[4];
    const float* wfc  = (const float*)d_in[5];
    const float* bfc  = (const float*)d_in[6];
    float* out = (float*)d_out;

    hipLaunchKernelGGL(aether_gru_kernel, dim3(1), dim3(1024), 0, stream,
                       x, wih, whh, bih, bhh, wfc, bfc, out);
}

// Round 5
// 44008.633 us; speedup vs baseline: 1.3101x; 1.3101x over previous
//
#include <hip/hip_runtime.h>
#include <stdint.h>
#include <stddef.h>

typedef _Float16 h2 __attribute__((ext_vector_type(2)));

#define T_STEPS 32768
#define HDIM    256

__device__ __forceinline__ float sigmoidf_(float x) {
    return 1.0f / (1.0f + __expf(-x));
}
__device__ __forceinline__ float tanhf_(float x) {
    float e2 = __expf(2.0f * x);
    return 1.0f - 2.0f / (e2 + 1.0f);
}
__device__ __forceinline__ h2 bc_(uint32_t u) { return __builtin_bit_cast(h2, u); }

// One block, 512 threads = 8 waves = 2 waves/SIMD.
// KEY FIX: __launch_bounds__ 2nd arg behaves as min BLOCKS per CU (CUDA
// semantics) on this toolchain — R2's (512,2) produced a 16-wave/CU target and
// a 128-VGPR cap; R4's (1024,4) produced 64. (512,1) -> 8 waves/CU ->
// 2 waves/SIMD -> 256-VGPR budget; our live set is ~230 -> no spill.
// Thread (wave w, lane l): column-half hq = l>>5, result-row ri = w*32+(l&31).
// Owns GRU rows {ri, 256+ri, 512+ri}, columns [hq*128, hq*128+128):
// 3 x 64 f16-pair weight registers, asm-pinned. Halves combined with one
// shfl_down(32) per gate. h is f16 in double-buffered LDS (broadcast reads);
// x staged in LDS (128 KB).
__global__ __launch_bounds__(512, 1)
void aether_gru_kernel(const float* __restrict__ xg,
                       const float* __restrict__ wih,
                       const float* __restrict__ whh,
                       const float* __restrict__ bih,
                       const float* __restrict__ bhh,
                       const float* __restrict__ wfc,
                       const float* __restrict__ bfc,
                       float* __restrict__ out) {
    const int tid  = threadIdx.x;
    const int lane = tid & 63;
    const int w    = tid >> 6;              // wave 0..7
    const int hq   = lane >> 5;             // column half 0/1
    const int ri   = w * 32 + (lane & 31);  // result row 0..255

    __shared__ float xlds[T_STEPS + 2];
    __shared__ __align__(16) _Float16 hbuf[2][HDIM];
    __shared__ float pp[2][8];

    // ---- stage x into LDS (coalesced float4) ----
    {
        const float4* xs4 = (const float4*)xg;
        float4* xd4 = (float4*)xlds;
        #pragma unroll
        for (int j = 0; j < T_STEPS / 4 / 512; ++j)
            xd4[tid + 512 * j] = xs4[tid + 512 * j];
        if (tid == 0) { xlds[T_STEPS] = 0.0f; xlds[T_STEPS + 1] = 0.0f; }
    }

    // ---- weights: 3 gates x 64 f16-pairs (128 cols each), bit-packed ----
    uint32_t wr[64], wz[64], wn[64];
    {
        const float2* p = (const float2*)(whh + (size_t)ri * HDIM + hq * 128);
        #pragma unroll
        for (int k = 0; k < 64; ++k) {
            float2 v = p[k]; h2 q; q.x = (_Float16)v.x; q.y = (_Float16)v.y;
            wr[k] = __builtin_bit_cast(uint32_t, q);
        }
    }
    {
        const float2* p = (const float2*)(whh + (size_t)(HDIM + ri) * HDIM + hq * 128);
        #pragma unroll
        for (int k = 0; k < 64; ++k) {
            float2 v = p[k]; h2 q; q.x = (_Float16)v.x; q.y = (_Float16)v.y;
            wz[k] = __builtin_bit_cast(uint32_t, q);
        }
    }
    {
        const float2* p = (const float2*)(whh + (size_t)(2 * HDIM + ri) * HDIM + hq * 128);
        #pragma unroll
        for (int k = 0; k < 64; ++k) {
            float2 v = p[k]; h2 q; q.x = (_Float16)v.x; q.y = (_Float16)v.y;
            wn[k] = __builtin_bit_cast(uint32_t, q);
        }
    }
    // pin: forces residency, blocks sinking/remat of the staging loads
    #pragma unroll
    for (int k = 0; k < 64; ++k) {
        asm volatile("" : "+v"(wr[k]));
        asm volatile("" : "+v"(wz[k]));
        asm volatile("" : "+v"(wn[k]));
    }

    // per-result-row scalar constants
    const float wxr = wih[2 * ri],              wdr = wih[2 * ri + 1];
    const float wxz = wih[2 * (HDIM + ri)],     wdz = wih[2 * (HDIM + ri) + 1];
    const float wxn = wih[2 * (2 * HDIM + ri)], wdn = wih[2 * (2 * HDIM + ri) + 1];
    const float br = bih[ri], bz = bih[HDIM + ri], bn = bih[2 * HDIM + ri];
    // b_hh folded into the accumulator of column-half 0 only
    const float cr = (hq == 0) ? bhh[ri] : 0.0f;
    const float cz = (hq == 0) ? bhh[HDIM + ri] : 0.0f;
    const float cn = (hq == 0) ? bhh[2 * HDIM + ri] : 0.0f;
    const float wf = wfc[ri];
    const float bf = bfc[0];

    if (tid < HDIM) hbuf[0][tid] = (_Float16)0.0f;
    __syncthreads();

    // ---- sequential state (uniform across threads -> uniform branches) ----
    float hprev    = 0.0f;
    float last_val = xlds[0] + 1.24f;       // xs[0] + (2*THRESHOLD + 1.0)
    float last_t   = 0.0f;
    int   cnt      = 0;
    int   cur      = 0;                     // hbuf read index
    int   pe       = 0;                     // pp parity
    float cur_pred = 0.0f;

    float xc = xlds[0];
    float xn = xlds[1];

    float* recon = out;
    float* idxp  = out + T_STEPS + 1;

    for (int t = 0; t < T_STEPS; ++t) {
        float xf = xlds[t + 2];                      // LDS prefetch, 2 ahead
        const float tf = (float)t;
        const bool ev = fabsf(xc - last_val) >= 0.12f;

        if (ev) {
            const float dtv = (tf - last_t) * 0.01f;
            const float gir = fmaf(wxr, xc, fmaf(wdr, dtv, br));
            const float giz = fmaf(wxz, xc, fmaf(wdz, dtv, bz));
            const float gin = fmaf(wxn, xc, fmaf(wdn, dtv, bn));

            float ar = cr, az = cz, an = cn;
            const uint4* hb = (const uint4*)(&hbuf[cur][hq * 128]);
            #pragma unroll
            for (int c = 0; c < 16; ++c) {
                uint4 q = hb[c];                     // 8 f16, broadcast per half-wave
                h2 p0 = __builtin_bit_cast(h2, q.x);
                h2 p1 = __builtin_bit_cast(h2, q.y);
                h2 p2 = __builtin_bit_cast(h2, q.z);
                h2 p3 = __builtin_bit_cast(h2, q.w);
                const int k = c * 4;
                ar = __builtin_amdgcn_fdot2(bc_(wr[k + 0]), p0, ar, false);
                az = __builtin_amdgcn_fdot2(bc_(wz[k + 0]), p0, az, false);
                an = __builtin_amdgcn_fdot2(bc_(wn[k + 0]), p0, an, false);
                ar = __builtin_amdgcn_fdot2(bc_(wr[k + 1]), p1, ar, false);
                az = __builtin_amdgcn_fdot2(bc_(wz[k + 1]), p1, az, false);
                an = __builtin_amdgcn_fdot2(bc_(wn[k + 1]), p1, an, false);
                ar = __builtin_amdgcn_fdot2(bc_(wr[k + 2]), p2, ar, false);
                az = __builtin_amdgcn_fdot2(bc_(wz[k + 2]), p2, az, false);
                an = __builtin_amdgcn_fdot2(bc_(wn[k + 2]), p2, an, false);
                ar = __builtin_amdgcn_fdot2(bc_(wr[k + 3]), p3, ar, false);
                az = __builtin_amdgcn_fdot2(bc_(wz[k + 3]), p3, az, false);
                an = __builtin_amdgcn_fdot2(bc_(wn[k + 3]), p3, an, false);
            }
            // combine column-halves: low 32 lanes get full sums
            ar += __shfl_down(ar, 32);
            az += __shfl_down(az, 32);
            an += __shfl_down(an, 32);

            const float r = sigmoidf_(gir + ar);
            const float z = sigmoidf_(giz + az);
            const float n = tanhf_(fmaf(r, an, gin));
            const float hnew = fmaf(z, hprev, (1.0f - z) * n);
            hprev = hnew;                            // valid on low-half lanes

            if ((lane >> 5) == 0) hbuf[cur ^ 1][ri] = (_Float16)hnew;

            // fc partial: zero upper half, reduce 32 -> lane 0
            float pv = (lane < 32) ? hnew * wf : 0.0f;
            pv += __shfl_down(pv, 16);
            pv += __shfl_down(pv, 8);
            pv += __shfl_down(pv, 4);
            pv += __shfl_down(pv, 2);
            pv += __shfl_down(pv, 1);
            if (lane == 0) pp[pe][w] = pv;
            if (tid == 0) idxp[cnt] = tf;            // ascending -> sorted

            last_val = xc;
            last_t   = tf;
            cnt++;

            __syncthreads();                          // publish hbuf + pp
            cur ^= 1;
            if (tid == 0) {
                const float* q = &pp[pe][0];
                cur_pred = ((q[0] + q[1]) + (q[2] + q[3]))
                         + ((q[4] + q[5]) + (q[6] + q[7])) + bf;
            }
            pe ^= 1;
        }

        if (tid == 0) recon[t] = cur_pred;            // piecewise-constant pred
        xc = xn; xn = xf;
    }

    if (tid == 0) out[T_STEPS] = (float)cnt;          // n_events
    for (int j = cnt + tid; j < T_STEPS; j += 512)
        idxp[j] = 32768.0f;                           // pad with T
}

extern "C" void kernel_launch(void* const* d_in, const int* in_sizes, int n_in,
                              void* d_out, int out_size, void* d_ws, size_t ws_size,
                              hipStream_t stream) {
    const float* x    = (const float*)d_in[0];
    const float* wih  = (const float*)d_in[1];
    const float* whh  = (const float*)d_in[2];
    const float* bih  = (const float*)d_in[3];
    const float* bhh  = (const float*)d_in[4];
    const float* wfc  = (const float*)d_in[5];
    const float* bfc  = (const float*)d_in[6];
    float* out = (float*)d_out;

    hipLaunchKernelGGL(aether_gru_kernel, dim3(1), dim3(512), 0, stream,
                       x, wih, whh, bih, bhh, wfc, bfc, out);
}